// Round 15
// baseline (13726.926 us; speedup 1.0000x reference)
//
#include <hip/hip_runtime.h>
#include <math.h>

// TD3ActorDSNN — f32 class-faithful, fused, round 15.
// Exactness invariants (validated r4-r6, r9, r11-r14):
//  - per-element k-ascending single-accumulator f32 chains for h0 and h1;
//    skipping k with mask==0 is bit-identical; order never changes.
//  - b in {0,1}: fma(b,w,acc) EXACT; fma(1,w,acc) == __fadd_rn(acc,w).
//  - recurrences: __fadd_rn(__fmul_rn(beta,state),h) (np mul-then-add).
//  - layer2/mem2: order-free (tanh input, tol 2e-2 >> 1e-6 noise).
// Codegen lessons (hard-won):
//  r7/r8/r13: multi-way CF or asm-tied accs => scratch spills (WRITE 0.8-10GB).
//  r6:       a 2-way UNIFORM branch, both sides straight-line touching all
//            accs, is allocator-safe (VGPR 48, 91% busy).
//  r10:      launch_bounds(256,8) => 32-VGPR cap => spill. Need (256,4).
//  r14:      dense SGPR selects (30/entry) saturate the CU-SHARED scalar
//            unit (1 SALU pipe per 4 SIMDs) => 47% VALU busy. b must be VALU.
// Round-15: r12 regime (VALU b, scalar fma, straight-line) + r6's full-mask
// fast path (36% of entries: 60 pure v_add, no b). ~85 VALU/entry vs 115.

typedef unsigned int u32;
typedef unsigned short u16;
typedef unsigned long long u64;

// ---- K1: h0 = inputs @ W0 (f32 fma chain) + fused mem0 recurrence -> s0bR ----
__global__ __launch_bounds__(256) void h0_kernel(
    const float* __restrict__ in, const float* __restrict__ W0,
    u16* __restrict__ s0bR) {
    __shared__ float Ls[32 * 512];
    int tid = threadIdx.x;
    int j = blockIdx.x * 256 + tid;
    int r0 = blockIdx.y * 32;
#pragma unroll
    for (int i = 0; i < 64; ++i) {
        int e = i * 256 + tid;
        Ls[e] = in[(size_t)(r0 + (e >> 9)) * 512 + (e & 511)];
    }
    __syncthreads();
    float acc[32];
#pragma unroll
    for (int r = 0; r < 32; ++r) acc[r] = 0.f;
    for (int k = 0; k < 512; ++k) {
        float w = W0[(size_t)k * 2048 + j];
#pragma unroll
        for (int r = 0; r < 32; ++r)
            acc[r] = __fmaf_rn(Ls[r * 512 + k], w, acc[r]);
    }
#pragma unroll
    for (int r = 0; r < 32; ++r) {
        float h = acc[r], mem = 0.f;
        u32 bits = 0;
#pragma unroll
        for (int t = 0; t < 15; ++t) {
            float nm = __fadd_rn(__fmul_rn(0.85f, mem), h);  // np: mul, then add
            bool sp = nm > 1.0f;
            bits |= (sp ? 1u : 0u) << t;
            mem = sp ? 0.f : nm;
        }
        s0bR[(size_t)(r0 + r) * 2048 + j] = (u16)bits;
    }
}

// ---- K1b: per-row active-k compaction (k-ascending preserved) ----
__global__ __launch_bounds__(256) void compact_kernel(
    const u16* __restrict__ s0bR, u32* __restrict__ list,
    int* __restrict__ ccnt) {
    int wv = threadIdx.x >> 6, lane = threadIdx.x & 63;
    int row = blockIdx.x * 4 + wv;
    const u16* mrow = s0bR + (size_t)row * 2048;
    u32* lrow = list + (size_t)row * 2048;
    int base = 0;
    for (int c = 0; c < 32; ++c) {
        int k = c * 64 + lane;
        u32 m = mrow[k];
        bool act = m != 0u;
        u64 b = __ballot(act ? 1 : 0);
        int pre = __popcll(b & ((1ull << lane) - 1ull));
        if (act) lrow[base + pre] = ((u32)k << 16) | m;
        base += __popcll(b);
    }
    int padded = (base + 1) & ~1;
    if (lane < (padded - base)) lrow[base + lane] = 0u;   // mask=0 -> no-op
    if (lane == 0) ccnt[row] = padded;
}

// ---- K2: FUSED h1 (15 steps) over ACTIVE k only + recurrence -> s1b ----
// Wave: 1 row x 256 cols (lane: 4 cols). Block: 4 rows. grid 8192:
// jb = id&7 (XCD-affine W1 slice), rblk = id>>3.
// Per entry: uniform 2-way (full vs sparse), both sides portable straight-line.
__global__ __launch_bounds__(256, 4) void h1_fused11(
    const float* __restrict__ W1, const u32* __restrict__ list,
    const int* __restrict__ ccnt, u16* __restrict__ s1b) {
    int id = blockIdx.x;
    int jb = id & 7, rblk = id >> 3;
    int lane = threadIdx.x & 63, wv = threadIdx.x >> 6;
    int row = rblk * 4 + wv;
    int j0 = jb * 256 + lane * 4;
    const float* wp = W1 + j0;
    const u32* lp = list + (size_t)row * 2048;
    int cnt = ccnt[row];                      // padded to multiple of 2

    float a0[15], a1[15], a2[15], a3[15];
#pragma unroll
    for (int t = 0; t < 15; ++t) { a0[t] = 0.f; a1[t] = 0.f; a2[t] = 0.f; a3[t] = 0.f; }

    for (int i = 0; i < cnt; i += 2) {
        uint2 e = *(const uint2*)(lp + i);    // 2 entries, wave-uniform addr
        u32 v0 = e.x, v1 = e.y;               // VGPR copy (v_bfe source)
        u32 s0 = __builtin_amdgcn_readfirstlane(v0);  // branch cond (1 SALU)
        u32 s1 = __builtin_amdgcn_readfirstlane(v1);
        // both w loads issued up front (latency overlap across the bodies)
        float4 w0 = *(const float4*)(wp + ((size_t)(s0 >> 16) << 11));
        float4 w1 = *(const float4*)(wp + ((size_t)(s1 >> 16) << 11));

        if ((s0 & 0x7FFFu) == 0x7FFFu) {      // full: all 15 steps spike
#pragma unroll
            for (int t = 0; t < 15; ++t) {
                a0[t] = __fadd_rn(a0[t], w0.x);
                a1[t] = __fadd_rn(a1[t], w0.y);
                a2[t] = __fadd_rn(a2[t], w0.z);
                a3[t] = __fadd_rn(a3[t], w0.w);
            }
        } else {                              // sparse: VALU b (bfe+cvt)
#pragma unroll
            for (int t = 0; t < 15; ++t) {
                float b = (float)((v0 >> t) & 1u);
                a0[t] = __fmaf_rn(b, w0.x, a0[t]);
                a1[t] = __fmaf_rn(b, w0.y, a1[t]);
                a2[t] = __fmaf_rn(b, w0.z, a2[t]);
                a3[t] = __fmaf_rn(b, w0.w, a3[t]);
            }
        }
        if ((s1 & 0x7FFFu) == 0x7FFFu) {
#pragma unroll
            for (int t = 0; t < 15; ++t) {
                a0[t] = __fadd_rn(a0[t], w1.x);
                a1[t] = __fadd_rn(a1[t], w1.y);
                a2[t] = __fadd_rn(a2[t], w1.z);
                a3[t] = __fadd_rn(a3[t], w1.w);
            }
        } else {
#pragma unroll
            for (int t = 0; t < 15; ++t) {
                float b = (float)((v1 >> t) & 1u);
                a0[t] = __fmaf_rn(b, w1.x, a0[t]);
                a1[t] = __fmaf_rn(b, w1.y, a1[t]);
                a2[t] = __fmaf_rn(b, w1.z, a2[t]);
                a3[t] = __fmaf_rn(b, w1.w, a3[t]);
            }
        }
    }

    // layer-1 recurrence per element (np rounding order) -> s1 bitmasks
    auto rec = [](const float* a) -> u16 {
        float syn = 0.f, mem = 0.f;
        u32 obits = 0;
#pragma unroll
        for (int t = 0; t < 15; ++t) {
            float ns = __fadd_rn(__fmul_rn(0.9f, syn), a[t]);
            float nm = __fadd_rn(__fmul_rn(0.85f, mem), ns);
            bool sp = nm > 1.0f;
            obits |= (sp ? 1u : 0u) << t;
            syn = ns;
            mem = sp ? 0.f : nm;
        }
        return (u16)obits;
    };
    u16 ob0 = rec(a0), ob1 = rec(a1), ob2 = rec(a2), ob3 = rec(a3);
    uint2 pk;
    pk.x = (u32)ob0 | ((u32)ob1 << 16);
    pk.y = (u32)ob2 | ((u32)ob3 << 16);
    *(uint2*)(s1b + (size_t)row * 2048 + j0) = pk;
}

// ---- K3: out = tanh(sum_t s1_t @ W2) (order-free reduction) ----
__global__ __launch_bounds__(256) void out_kernel(
    const u16* __restrict__ s1b, const float* __restrict__ W2,
    float* __restrict__ out) {
    __shared__ float P[4][15][8];
    int row = blockIdx.x;
    int tid = threadIdx.x, lane = tid & 63, wv = tid >> 6;
    const u16* srow = s1b + (size_t)row * 2048;
    union { uint4 v; u16 m[8]; } u;
    u.v = *(const uint4*)(srow + tid * 8);
#pragma unroll
    for (int t = 0; t < 15; ++t) {
        float a[8];
#pragma unroll
        for (int jj = 0; jj < 8; ++jj) a[jj] = 0.f;
#pragma unroll
        for (int kk = 0; kk < 8; ++kk) {
            const float* wr = W2 + (size_t)(tid * 8 + kk) * 8;
            if ((u.m[kk] >> t) & 1u) {
#pragma unroll
                for (int jj = 0; jj < 8; ++jj)
                    a[jj] = __fadd_rn(a[jj], wr[jj]);
            }
        }
#pragma unroll
        for (int jj = 0; jj < 8; ++jj) {
            float v = a[jj];
#pragma unroll
            for (int m = 1; m < 64; m <<= 1) v += __shfl_xor(v, m, 64);
            a[jj] = v;
        }
        if (lane == 0) {
#pragma unroll
            for (int jj = 0; jj < 8; ++jj) P[wv][t][jj] = a[jj];
        }
    }
    __syncthreads();
    if (tid < 8) {
        float m2 = 0.f;
#pragma unroll
        for (int t = 0; t < 15; ++t) {
            float s = __fadd_rn(__fadd_rn(P[0][t][tid], P[1][t][tid]),
                                __fadd_rn(P[2][t][tid], P[3][t][tid]));
            m2 = __fadd_rn(m2, s);
        }
        out[(size_t)row * 8 + tid] = tanhf(m2);
    }
}

extern "C" void kernel_launch(void* const* d_in, const int* in_sizes, int n_in,
                              void* d_out, int out_size, void* d_ws, size_t ws_size,
                              hipStream_t stream) {
    const float* inp = (const float*)d_in[0];
    const float* W0  = (const float*)d_in[1];
    const float* W1  = (const float*)d_in[2];
    const float* W2  = (const float*)d_in[3];
    float* out = (float*)d_out;
    char* ws = (char*)d_ws;

    u16* s0bR = (u16*)(ws + 0);            // 16,777,216  [row][k] 15-bit masks
    u16* s1b  = (u16*)(ws + 16777216);     // 16,777,216  [row][j] 15-bit masks
    u32* list = (u32*)(ws + 33554432);     // 33,554,432  [row][2048] (k<<16|mask)
    int* ccnt = (int*)(ws + 67108864);     //     16,384  padded counts
    if (ws_size < 67125248) return;        // ~64 MB scratch

    h0_kernel<<<dim3(8, 128), 256, 0, stream>>>(inp, W0, s0bR);
    compact_kernel<<<1024, 256, 0, stream>>>(s0bR, list, ccnt);
    h1_fused11<<<8192, 256, 0, stream>>>(W1, list, ccnt, s1b);
    out_kernel<<<4096, 256, 0, stream>>>(s1b, W2, out);
}

// Round 16
// 2650.014 us; speedup vs baseline: 5.1799x; 5.1799x over previous
//
#include <hip/hip_runtime.h>
#include <math.h>

// TD3ActorDSNN — f32 class-faithful, fused, round 16.
// Exactness invariants (validated r4-r6, r9, r11-r15):
//  - per-element k-ascending single-accumulator f32 chains for h0 and h1;
//    skipping k with mask==0 is bit-identical; order never changes.
//  - b in {0,1}: fma(b,w,acc) EXACT (b=1 -> RN(acc+w) == validated add;
//    b=0 -> acc unchanged; acc never -0 in a +0-seeded add chain).
//  - masks are PERIODIC (mem0 resets to exact 0): mask determined by period
//    n = ctz(mask)+1; bit t set iff (t+1)%n==0. Validated by r8's pass.
//  - recurrences: __fadd_rn(__fmul_rn(beta,state),h) (np mul-then-add).
//  - layer2/mem2: order-free (tanh input, tol 2e-2 >> 1e-6 noise).
// Codegen ledger (hard-won):
//  SPILL (WRITE 0.8-10GB): r7/r8 multi-way CF; r13 asm+branch; r15 2-way
//    branch; r10 launch_bounds(,8) 32-VGPR cap. ANY branch on the 60 accs.
//  SAFE (~16MB WRITE): r9/r11/r12/r14 single-BB portable bodies, (256,4).
//  r14: dense SGPR selects saturate the CU-SHARED scalar pipe (1 SALU per
//    4 SIMDs). b must not cost SALU per t either.
// Round-16: b comes from MEMORY — a 1KB LUT (16 periods x 16 f32) loaded as
// broadcast float4s (VMEM pipe). Body = exactly 60 scalar fma, no b ALU at
// all. Entry = k<<16 | n; padding n=0 -> lut row 0 = zeros (exact no-op).

typedef unsigned int u32;
typedef unsigned short u16;
typedef unsigned long long u64;

// ---- K1: h0 = inputs @ W0 (f32 fma chain) + fused mem0 recurrence -> s0bR ----
__global__ __launch_bounds__(256) void h0_kernel(
    const float* __restrict__ in, const float* __restrict__ W0,
    u16* __restrict__ s0bR) {
    __shared__ float Ls[32 * 512];
    int tid = threadIdx.x;
    int j = blockIdx.x * 256 + tid;
    int r0 = blockIdx.y * 32;
#pragma unroll
    for (int i = 0; i < 64; ++i) {
        int e = i * 256 + tid;
        Ls[e] = in[(size_t)(r0 + (e >> 9)) * 512 + (e & 511)];
    }
    __syncthreads();
    float acc[32];
#pragma unroll
    for (int r = 0; r < 32; ++r) acc[r] = 0.f;
    for (int k = 0; k < 512; ++k) {
        float w = W0[(size_t)k * 2048 + j];
#pragma unroll
        for (int r = 0; r < 32; ++r)
            acc[r] = __fmaf_rn(Ls[r * 512 + k], w, acc[r]);
    }
#pragma unroll
    for (int r = 0; r < 32; ++r) {
        float h = acc[r], mem = 0.f;
        u32 bits = 0;
#pragma unroll
        for (int t = 0; t < 15; ++t) {
            float nm = __fadd_rn(__fmul_rn(0.85f, mem), h);  // np: mul, then add
            bool sp = nm > 1.0f;
            bits |= (sp ? 1u : 0u) << t;
            mem = sp ? 0.f : nm;
        }
        s0bR[(size_t)(r0 + r) * 2048 + j] = (u16)bits;
    }
}

// ---- K1b: active-k compaction (k-ascending) + b-LUT init ----
// entry = k<<16 | n, n = ctz(mask)+1 (periodic masks, r8-validated).
__global__ __launch_bounds__(256) void compact_kernel(
    const u16* __restrict__ s0bR, u32* __restrict__ list,
    int* __restrict__ ccnt, float* __restrict__ lut) {
    int wv = threadIdx.x >> 6, lane = threadIdx.x & 63;
    if (blockIdx.x == 0) {    // fill 16x16 LUT: lut[n][t] = ((t+1)%n==0)
        int n = threadIdx.x >> 4, t = threadIdx.x & 15;
        lut[threadIdx.x] = (n >= 1 && t < 15 && ((t + 1) % n == 0)) ? 1.0f : 0.0f;
    }
    int row = blockIdx.x * 4 + wv;
    const u16* mrow = s0bR + (size_t)row * 2048;
    u32* lrow = list + (size_t)row * 2048;
    int base = 0;
    for (int c = 0; c < 32; ++c) {
        int k = c * 64 + lane;
        u32 m = mrow[k];
        bool act = m != 0u;
        u64 b = __ballot(act ? 1 : 0);
        int pre = __popcll(b & ((1ull << lane) - 1ull));
        if (act) lrow[base + pre] = ((u32)k << 16) | (u32)(__builtin_ctz(m | 0x10000u) + 1);
        base += __popcll(b);
    }
    int padded = (base + 1) & ~1;
    if (lane < (padded - base)) lrow[base + lane] = 0u;   // n=0 -> lut zeros
    if (lane == 0) ccnt[row] = padded;
}

// ---- K2: FUSED h1 (15 steps) over ACTIVE k only + recurrence -> s1b ----
// Wave: 1 row x 256 cols (lane: 4 cols). Block: 4 rows. grid 8192:
// jb = id&7 (XCD-affine W1 slice), rblk = id>>3.
// Single straight-line body; b via broadcast LUT loads; 60 fma/entry.
__global__ __launch_bounds__(256, 4) void h1_fused12(
    const float* __restrict__ W1, const u32* __restrict__ list,
    const int* __restrict__ ccnt, const float* __restrict__ lut,
    u16* __restrict__ s1b) {
    int id = blockIdx.x;
    int jb = id & 7, rblk = id >> 3;
    int lane = threadIdx.x & 63, wv = threadIdx.x >> 6;
    int row = rblk * 4 + wv;
    int j0 = jb * 256 + lane * 4;
    const float* wp = W1 + j0;
    const u32* lp = list + (size_t)row * 2048;
    int cnt = ccnt[row];                      // padded to multiple of 2

    float a0[15], a1[15], a2[15], a3[15];
#pragma unroll
    for (int t = 0; t < 15; ++t) { a0[t] = 0.f; a1[t] = 0.f; a2[t] = 0.f; a3[t] = 0.f; }

#define FMA4(BT, T, W)                                   \
    a0[T] = __fmaf_rn(BT, W.x, a0[T]);                   \
    a1[T] = __fmaf_rn(BT, W.y, a1[T]);                   \
    a2[T] = __fmaf_rn(BT, W.z, a2[T]);                   \
    a3[T] = __fmaf_rn(BT, W.w, a3[T]);

#define BODY(W, BA, BB, BC, BD)                          \
    FMA4(BA.x, 0, W) FMA4(BA.y, 1, W) FMA4(BA.z, 2, W) FMA4(BA.w, 3, W) \
    FMA4(BB.x, 4, W) FMA4(BB.y, 5, W) FMA4(BB.z, 6, W) FMA4(BB.w, 7, W) \
    FMA4(BC.x, 8, W) FMA4(BC.y, 9, W) FMA4(BC.z,10, W) FMA4(BC.w,11, W) \
    FMA4(BD.x,12, W) FMA4(BD.y,13, W) FMA4(BD.z,14, W)

    for (int i = 0; i < cnt; i += 2) {
        uint2 e = *(const uint2*)(lp + i);    // 2 entries, wave-uniform addr
        u32 s0 = __builtin_amdgcn_readfirstlane(e.x);
        u32 s1 = __builtin_amdgcn_readfirstlane(e.y);
        // w loads (L2) issued up front for latency overlap
        float4 w0 = *(const float4*)(wp + ((size_t)(s0 >> 16) << 11));
        float4 w1 = *(const float4*)(wp + ((size_t)(s1 >> 16) << 11));
        // b vectors: broadcast loads from 1KB L1-hot LUT (VMEM, zero ALU)
        const float4* bp0 = (const float4*)(lut + ((s0 & 15u) << 4));
        const float4* bp1 = (const float4*)(lut + ((s1 & 15u) << 4));
        float4 ba0 = bp0[0], bb0 = bp0[1], bc0 = bp0[2], bd0 = bp0[3];
        float4 ba1 = bp1[0], bb1 = bp1[1], bc1 = bp1[2], bd1 = bp1[3];
        BODY(w0, ba0, bb0, bc0, bd0)
        BODY(w1, ba1, bb1, bc1, bd1)
    }
#undef BODY
#undef FMA4

    // layer-1 recurrence per element (np rounding order) -> s1 bitmasks
    auto rec = [](const float* a) -> u16 {
        float syn = 0.f, mem = 0.f;
        u32 obits = 0;
#pragma unroll
        for (int t = 0; t < 15; ++t) {
            float ns = __fadd_rn(__fmul_rn(0.9f, syn), a[t]);
            float nm = __fadd_rn(__fmul_rn(0.85f, mem), ns);
            bool sp = nm > 1.0f;
            obits |= (sp ? 1u : 0u) << t;
            syn = ns;
            mem = sp ? 0.f : nm;
        }
        return (u16)obits;
    };
    u16 ob0 = rec(a0), ob1 = rec(a1), ob2 = rec(a2), ob3 = rec(a3);
    uint2 pk;
    pk.x = (u32)ob0 | ((u32)ob1 << 16);
    pk.y = (u32)ob2 | ((u32)ob3 << 16);
    *(uint2*)(s1b + (size_t)row * 2048 + j0) = pk;
}

// ---- K3: out = tanh(sum_t s1_t @ W2) (order-free reduction) ----
__global__ __launch_bounds__(256) void out_kernel(
    const u16* __restrict__ s1b, const float* __restrict__ W2,
    float* __restrict__ out) {
    __shared__ float P[4][15][8];
    int row = blockIdx.x;
    int tid = threadIdx.x, lane = tid & 63, wv = tid >> 6;
    const u16* srow = s1b + (size_t)row * 2048;
    union { uint4 v; u16 m[8]; } u;
    u.v = *(const uint4*)(srow + tid * 8);
#pragma unroll
    for (int t = 0; t < 15; ++t) {
        float a[8];
#pragma unroll
        for (int jj = 0; jj < 8; ++jj) a[jj] = 0.f;
#pragma unroll
        for (int kk = 0; kk < 8; ++kk) {
            const float* wr = W2 + (size_t)(tid * 8 + kk) * 8;
            if ((u.m[kk] >> t) & 1u) {
#pragma unroll
                for (int jj = 0; jj < 8; ++jj)
                    a[jj] = __fadd_rn(a[jj], wr[jj]);
            }
        }
#pragma unroll
        for (int jj = 0; jj < 8; ++jj) {
            float v = a[jj];
#pragma unroll
            for (int m = 1; m < 64; m <<= 1) v += __shfl_xor(v, m, 64);
            a[jj] = v;
        }
        if (lane == 0) {
#pragma unroll
            for (int jj = 0; jj < 8; ++jj) P[wv][t][jj] = a[jj];
        }
    }
    __syncthreads();
    if (tid < 8) {
        float m2 = 0.f;
#pragma unroll
        for (int t = 0; t < 15; ++t) {
            float s = __fadd_rn(__fadd_rn(P[0][t][tid], P[1][t][tid]),
                                __fadd_rn(P[2][t][tid], P[3][t][tid]));
            m2 = __fadd_rn(m2, s);
        }
        out[(size_t)row * 8 + tid] = tanhf(m2);
    }
}

extern "C" void kernel_launch(void* const* d_in, const int* in_sizes, int n_in,
                              void* d_out, int out_size, void* d_ws, size_t ws_size,
                              hipStream_t stream) {
    const float* inp = (const float*)d_in[0];
    const float* W0  = (const float*)d_in[1];
    const float* W1  = (const float*)d_in[2];
    const float* W2  = (const float*)d_in[3];
    float* out = (float*)d_out;
    char* ws = (char*)d_ws;

    u16*   s0bR = (u16*)(ws + 0);          // 16,777,216  [row][k] 15-bit masks
    u16*   s1b  = (u16*)(ws + 16777216);   // 16,777,216  [row][j] 15-bit masks
    u32*   list = (u32*)(ws + 33554432);   // 33,554,432  [row][2048] (k<<16|n)
    int*   ccnt = (int*)(ws + 67108864);   //     16,384  padded counts
    float* lut  = (float*)(ws + 67125248); //      1,024  16x16 b-LUT
    if (ws_size < 67126272) return;        // ~64 MB scratch

    h0_kernel<<<dim3(8, 128), 256, 0, stream>>>(inp, W0, s0bR);
    compact_kernel<<<1024, 256, 0, stream>>>(s0bR, list, ccnt, lut);
    h1_fused12<<<8192, 256, 0, stream>>>(W1, list, ccnt, lut, s1b);
    out_kernel<<<4096, 256, 0, stream>>>(s1b, W2, out);
}